// Round 2
// baseline (990.078 us; speedup 1.0000x reference)
//
#include <hip/hip_runtime.h>

typedef unsigned short u16;
typedef unsigned int   u32;
typedef __bf16 bf16x8 __attribute__((ext_vector_type(8)));
typedef float  f32x4  __attribute__((ext_vector_type(4)));
typedef u16    u16x8  __attribute__((ext_vector_type(8)));

#define S_   2048
#define D_   1024
#define H_   16
#define M_   4096

// log2-domain softmax constants: p = exp2(s*SCALE2 + mask*MASKC - SHIFT2)
// (= exp(s*0.125 + mask*(-1e9) - 8); fixed shift 8 replaces the row max —
//  softmax is shift-invariant, |s*0.125| <~ 12 so exp stays in fp32 range)
#define SCALE2 0.18033688011112042f
#define MASKC  (-1.4426950408889634e9f)
#define SHIFT2 11.541560327111707f

__device__ __forceinline__ u16 f2b(float f){
  union { float f; u32 i; } x; x.f = f;
  u32 u = x.i;
  u32 r = (u + 0x7fffu + ((u >> 16) & 1u)) >> 16;
  return (u16)r;
}
// async global->LDS, 16B per lane; LDS dest is wave-uniform base + lane*16
__device__ __forceinline__ void async16(u16* lds, const u16* g){
  __builtin_amdgcn_global_load_lds((const __attribute__((address_space(1))) void*)g,
                                   (__attribute__((address_space(3))) void*)lds, 16, 0, 0);
}
__device__ __forceinline__ f32x4 mma16(bf16x8 a, bf16x8 b, f32x4 c){
  return __builtin_amdgcn_mfma_f32_16x16x32_bf16(a, b, c, 0, 0, 0);
}
__device__ __forceinline__ bf16x8 ld_frag_u16(const u16* p){
  u16x8 v = *(const u16x8*)p;
  return __builtin_bit_cast(bf16x8, v);
}

// ---------------------------------------------------------------------------
// prep: fused  (a) q/k/v fp32->bf16 cvt   [blocks 0..6143]
//              (b) weight transpose+cvt   [blocks 6144..7167]
// ---------------------------------------------------------------------------
__global__ __launch_bounds__(256) void prep(
    const float* __restrict__ q, const float* __restrict__ k, const float* __restrict__ v,
    u16* __restrict__ qb, u16* __restrict__ kb, u16* __restrict__ vb,
    const float* __restrict__ w0, const float* __restrict__ w1,
    const float* __restrict__ w2, const float* __restrict__ w3,
    u16* __restrict__ t0, u16* __restrict__ t1,
    u16* __restrict__ t2, u16* __restrict__ t3)
{
  const int bid = blockIdx.x;
  if (bid < 6144){
    const int which = bid >> 11;           // 0..2 (2048 blocks each)
    const int bx = bid & 2047;
    const float* x = (which == 0) ? q : (which == 1) ? k : v;
    u16* y = (which == 0) ? qb : (which == 1) ? kb : vb;
    size_t i = (size_t)bx * 256 + threadIdx.x;   // 8 elems per thread
    const f32x4* p = (const f32x4*)(x + i * 8);
    f32x4 a = p[0], b = p[1];
    u16x8 o;
    o[0] = f2b(a[0]); o[1] = f2b(a[1]); o[2] = f2b(a[2]); o[3] = f2b(a[3]);
    o[4] = f2b(b[0]); o[5] = f2b(b[1]); o[6] = f2b(b[2]); o[7] = f2b(b[3]);
    *(u16x8*)(y + i * 8) = o;
  } else {
    const int b = bid - 6144;              // 0..1023
    const int z = b >> 8, rem = b & 255, by = rem >> 4, bx = rem & 15;
    const float* W; u16* T;
    switch (z){
      case 0: W = w0; T = t0; break;
      case 1: W = w1; T = t1; break;
      case 2: W = w2; T = t2; break;
      default: W = w3; T = t3; break;
    }
    __shared__ u16 tile[64][65];
    const int t = threadIdx.x;
    const int r0 = by * 64, c0 = bx * 64;
    const int row = t >> 2, cg = t & 3;
    const float* src = W + (size_t)(r0 + row) * D_ + c0 + cg * 16;
    f32x4 a0 = *(const f32x4*)(src + 0);
    f32x4 a1 = *(const f32x4*)(src + 4);
    f32x4 a2 = *(const f32x4*)(src + 8);
    f32x4 a3 = *(const f32x4*)(src + 12);
    #pragma unroll
    for (int e = 0; e < 4; ++e){
      tile[row][cg*16 +      e] = f2b(a0[e]);
      tile[row][cg*16 +  4 + e] = f2b(a1[e]);
      tile[row][cg*16 +  8 + e] = f2b(a2[e]);
      tile[row][cg*16 + 12 + e] = f2b(a3[e]);
    }
    __syncthreads();
    u16* dst = T + (size_t)(c0 + row) * D_ + r0 + cg * 16;
    u16x8 oa, ob;
    #pragma unroll
    for (int e = 0; e < 8; ++e){ oa[e] = tile[cg*16 + e][row]; ob[e] = tile[cg*16 + 8 + e][row]; }
    *(u16x8*)dst = oa;
    *(u16x8*)(dst + 8) = ob;
  }
}

// ---------------------------------------------------------------------------
// gemm_qkv: fused Q/K/V projections, z selects input/weight/bias/output.
// All outputs head-split bf16 [(b*16+h), s, 64] (coalesced epilogue).
// grid (32, 8, 3) = 768 blocks -> 3 blocks/CU.
// ---------------------------------------------------------------------------
__global__ __launch_bounds__(256) void gemm_qkv(
    const u16* __restrict__ qb, const u16* __restrict__ kb, const u16* __restrict__ vb,
    const u16* __restrict__ wqT, const u16* __restrict__ wkT, const u16* __restrict__ wvT,
    const float* __restrict__ bq, const float* __restrict__ bk, const float* __restrict__ bv,
    u16* __restrict__ Qh, u16* __restrict__ Kh, u16* __restrict__ Vh)
{
  __shared__ __attribute__((aligned(16))) u16 As[128 * 64];
  __shared__ __attribute__((aligned(16))) u16 Bs[128 * 64];
  const u16 *A, *Bt; const float* bias; u16* Cb;
  switch (blockIdx.z){
    case 0: A = qb; Bt = wqT; bias = bq; Cb = Qh; break;
    case 1: A = kb; Bt = wkT; bias = bk; Cb = Kh; break;
    default: A = vb; Bt = wvT; bias = bv; Cb = Vh; break;
  }
  const int tid = threadIdx.x;
  const int wave = tid >> 6, lane = tid & 63, ln = lane & 15, quad = lane >> 4;
  const int wm = wave >> 1, wn = wave & 1;
  const int m0 = blockIdx.x * 128, n0 = blockIdx.y * 128;

  f32x4 acc[4][4];
  #pragma unroll
  for (int i = 0; i < 4; ++i)
    #pragma unroll
    for (int j = 0; j < 4; ++j) acc[i][j] = (f32x4){0.f, 0.f, 0.f, 0.f};

  for (int kt = 0; kt < D_; kt += 64){
    #pragma unroll
    for (int it = 0; it < 4; ++it){
      int i = it * 256 + tid;
      int r = i >> 3, c = i & 7, cs = c ^ (r & 7);
      async16(&As[i * 8], &A [(size_t)(m0 + r) * D_ + kt + cs * 8]);
      async16(&Bs[i * 8], &Bt[(size_t)(n0 + r) * D_ + kt + cs * 8]);
    }
    __syncthreads();
    #pragma unroll
    for (int kk = 0; kk < 2; ++kk){
      bf16x8 af[4], bfr[4];
      #pragma unroll
      for (int i4 = 0; i4 < 4; ++i4){
        int row = wm * 64 + i4 * 16 + ln;
        af[i4] = ld_frag_u16(&As[row * 64 + ((kk * 4 + quad) ^ (row & 7)) * 8]);
      }
      #pragma unroll
      for (int j4 = 0; j4 < 4; ++j4){
        int row = wn * 64 + j4 * 16 + ln;
        bfr[j4] = ld_frag_u16(&Bs[row * 64 + ((kk * 4 + quad) ^ (row & 7)) * 8]);
      }
      #pragma unroll
      for (int i4 = 0; i4 < 4; ++i4)
        #pragma unroll
        for (int j4 = 0; j4 < 4; ++j4)
          acc[i4][j4] = mma16(af[i4], bfr[j4], acc[i4][j4]);
    }
    __syncthreads();
  }

  #pragma unroll
  for (int j4 = 0; j4 < 4; ++j4){
    int nidx = n0 + wn * 64 + j4 * 16 + ln;
    float biasv = bias[nidx];
    #pragma unroll
    for (int i4 = 0; i4 < 4; ++i4){
      #pragma unroll
      for (int rg = 0; rg < 4; ++rg){
        int r = m0 + wm * 64 + i4 * 16 + quad * 4 + rg;
        float val = acc[i4][j4][rg] + biasv;
        int bb = r >> 11, s = r & 2047, hh = nidx >> 6, dc = nidx & 63;
        Cb[((size_t)(bb * H_ + hh) * S_ + s) * 64 + dc] = f2b(val);
      }
    }
  }
}

// ---------------------------------------------------------------------------
// vtrans: Vh [bh, s, 64] -> Vt [bh, 64, s]; LDS-tiled, coalesced both sides.
// ---------------------------------------------------------------------------
__global__ __launch_bounds__(256) void vtrans(
    const u16* __restrict__ Vh, u16* __restrict__ Vt)
{
  __shared__ u16 tile[64][72];
  const int bh = blockIdx.y, s0 = blockIdx.x * 64;
  const int t = threadIdx.x;
  const int row = t >> 2, cg = t & 3;
  const u16* src = Vh + ((size_t)bh * S_ + s0 + row) * 64 + cg * 16;
  u16x8 a0 = *(const u16x8*)src;
  u16x8 a1 = *(const u16x8*)(src + 8);
  #pragma unroll
  for (int e = 0; e < 8; ++e){ tile[row][cg*16 + e] = a0[e]; tile[row][cg*16 + 8 + e] = a1[e]; }
  __syncthreads();
  u16* dst = Vt + ((size_t)bh * 64 + row) * S_ + s0 + cg * 16;
  u16x8 oa, ob;
  #pragma unroll
  for (int e = 0; e < 8; ++e){ oa[e] = tile[cg*16 + e][row]; ob[e] = tile[cg*16 + 8 + e][row]; }
  *(u16x8*)dst = oa;
  *(u16x8*)(dst + 8) = ob;
}

// ---------------------------------------------------------------------------
// gemm_o: output projection, fp32 C. Double-buffered LDS prefetch.
// ---------------------------------------------------------------------------
__global__ __launch_bounds__(256) void gemm_o(
    const u16* __restrict__ A, const u16* __restrict__ Bt,
    const float* __restrict__ bias, float* __restrict__ Cf)
{
  __shared__ __attribute__((aligned(16))) u16 As[2][128 * 64];
  __shared__ __attribute__((aligned(16))) u16 Bs[2][128 * 64];
  const int tid = threadIdx.x;
  const int wave = tid >> 6, lane = tid & 63, ln = lane & 15, quad = lane >> 4;
  const int wm = wave >> 1, wn = wave & 1;
  const int m0 = blockIdx.x * 128, n0 = blockIdx.y * 128;

  f32x4 acc[4][4];
  #pragma unroll
  for (int i = 0; i < 4; ++i)
    #pragma unroll
    for (int j = 0; j < 4; ++j) acc[i][j] = (f32x4){0.f, 0.f, 0.f, 0.f};

  #pragma unroll
  for (int it = 0; it < 4; ++it){
    int i = it * 256 + tid;
    int r = i >> 3, c = i & 7, cs = c ^ (r & 7);
    async16(&As[0][i * 8], &A [(size_t)(m0 + r) * D_ + cs * 8]);
    async16(&Bs[0][i * 8], &Bt[(size_t)(n0 + r) * D_ + cs * 8]);
  }
  __syncthreads();

  int cur = 0;
  for (int kt = 0; kt < D_; kt += 64){
    if (kt + 64 < D_){
      int nb = cur ^ 1;
      #pragma unroll
      for (int it = 0; it < 4; ++it){
        int i = it * 256 + tid;
        int r = i >> 3, c = i & 7, cs = c ^ (r & 7);
        async16(&As[nb][i * 8], &A [(size_t)(m0 + r) * D_ + kt + 64 + cs * 8]);
        async16(&Bs[nb][i * 8], &Bt[(size_t)(n0 + r) * D_ + kt + 64 + cs * 8]);
      }
    }
    #pragma unroll
    for (int kk = 0; kk < 2; ++kk){
      bf16x8 af[4], bfr[4];
      #pragma unroll
      for (int i4 = 0; i4 < 4; ++i4){
        int row = wm * 64 + i4 * 16 + ln;
        af[i4] = ld_frag_u16(&As[cur][row * 64 + ((kk * 4 + quad) ^ (row & 7)) * 8]);
      }
      #pragma unroll
      for (int j4 = 0; j4 < 4; ++j4){
        int row = wn * 64 + j4 * 16 + ln;
        bfr[j4] = ld_frag_u16(&Bs[cur][row * 64 + ((kk * 4 + quad) ^ (row & 7)) * 8]);
      }
      #pragma unroll
      for (int i4 = 0; i4 < 4; ++i4)
        #pragma unroll
        for (int j4 = 0; j4 < 4; ++j4)
          acc[i4][j4] = mma16(af[i4], bfr[j4], acc[i4][j4]);
    }
    __syncthreads();
    cur ^= 1;
  }

  #pragma unroll
  for (int j4 = 0; j4 < 4; ++j4){
    int nidx = n0 + wn * 64 + j4 * 16 + ln;
    float biasv = bias[nidx];
    #pragma unroll
    for (int i4 = 0; i4 < 4; ++i4){
      #pragma unroll
      for (int rg = 0; rg < 4; ++rg){
        int r = m0 + wm * 64 + i4 * 16 + quad * 4 + rg;
        Cf[(size_t)r * D_ + nidx] = acc[i4][j4][rg] + biasv;
      }
    }
  }
}

// ---------------------------------------------------------------------------
// Pass 1: softmax denominator, fixed shift. NO LDS, NO barriers: K fragments
// loaded straight from global (K per (b,h) = 256 KB, L2-resident); latency
// hidden by TLP (zero-LDS kernel -> max occupancy).
// ---------------------------------------------------------------------------
__global__ __launch_bounds__(256) void attn_stats(
    const u16* __restrict__ Qh, const u16* __restrict__ Kh,
    const float* __restrict__ maskp, float* __restrict__ lrow)
{
  const int tid = threadIdx.x;
  const int wave = tid >> 6, lane = tid & 63, ln = lane & 15, quad = lane >> 4;
  const int q0 = blockIdx.x * 64;
  const int bh = blockIdx.y;
  const int bsel = bh >> 4;

  // Q fragment: rows q0+wave*16+ln, k-cols quad*8 (+32)
  const u16* qp = &Qh[((size_t)bh * S_ + q0 + wave * 16 + ln) * 64 + quad * 8];
  bf16x8 aq0 = ld_frag_u16(qp);
  bf16x8 aq1 = ld_frag_u16(qp + 32);

  // K fragment pointers, one per j (rows j*16+ln), bumped 64 rows per tile
  const u16* kp0 = &Kh[((size_t)bh * S_ + ln) * 64 + quad * 8];
  const u16* kp1 = kp0 + 16 * 64;
  const u16* kp2 = kp0 + 32 * 64;
  const u16* kp3 = kp0 + 48 * 64;
  const float* mp = &maskp[bsel * S_ + ln];

  float lsum[4] = {0.f, 0.f, 0.f, 0.f};
  for (int n0 = 0; n0 < S_; n0 += 64){
    float mv0 = mp[ 0] * MASKC - SHIFT2;
    float mv1 = mp[16] * MASKC - SHIFT2;
    float mv2 = mp[32] * MASKC - SHIFT2;
    float mv3 = mp[48] * MASKC - SHIFT2;
    bf16x8 b00 = ld_frag_u16(kp0), b01 = ld_frag_u16(kp0 + 32);
    bf16x8 b10 = ld_frag_u16(kp1), b11 = ld_frag_u16(kp1 + 32);
    bf16x8 b20 = ld_frag_u16(kp2), b21 = ld_frag_u16(kp2 + 32);
    bf16x8 b30 = ld_frag_u16(kp3), b31 = ld_frag_u16(kp3 + 32);
    f32x4 a0 = {0.f,0.f,0.f,0.f}, a1 = a0, a2 = a0, a3 = a0;
    a0 = mma16(aq0, b00, a0); a0 = mma16(aq1, b01, a0);
    a1 = mma16(aq0, b10, a1); a1 = mma16(aq1, b11, a1);
    a2 = mma16(aq0, b20, a2); a2 = mma16(aq1, b21, a2);
    a3 = mma16(aq0, b30, a3); a3 = mma16(aq1, b31, a3);
    #pragma unroll
    for (int rg = 0; rg < 4; ++rg){
      lsum[rg] += exp2f(a0[rg] * SCALE2 + mv0) + exp2f(a1[rg] * SCALE2 + mv1)
                + exp2f(a2[rg] * SCALE2 + mv2) + exp2f(a3[rg] * SCALE2 + mv3);
    }
    kp0 += 64 * 64; kp1 += 64 * 64; kp2 += 64 * 64; kp3 += 64 * 64;
    mp += 64;
  }
  #pragma unroll
  for (int rg = 0; rg < 4; ++rg){
    float s = lsum[rg];
    s += __shfl_xor(s, 1);
    s += __shfl_xor(s, 2);
    s += __shfl_xor(s, 4);
    s += __shfl_xor(s, 8);
    if (ln == 0)
      lrow[bh * S_ + q0 + wave * 16 + quad * 4 + rg] = s;
  }
}

// ---------------------------------------------------------------------------
// Pass 2: p = exp2(s*c + mv)/l -> attn (fp32); per-wave LDS P round-trip
// (lgkmcnt-ordered, no barrier); PV accumulate -> OH bf16 [B,S,D].
// K/V fragments straight from global (L2-resident). NO __syncthreads at all.
// ---------------------------------------------------------------------------
__global__ __launch_bounds__(256) void attn_pv(
    const u16* __restrict__ Qh, const u16* __restrict__ Kh, const u16* __restrict__ Vt,
    const float* __restrict__ maskp, const float* __restrict__ lrow,
    float* __restrict__ attn, u16* __restrict__ OH)
{
  __shared__ __attribute__((aligned(16))) u16 Ps[4][16 * 72];
  const int tid = threadIdx.x;
  const int wave = tid >> 6, lane = tid & 63, ln = lane & 15, quad = lane >> 4;
  const int q0 = blockIdx.x * 64;
  const int bh = blockIdx.y;
  const int bsel = bh >> 4;

  const u16* qp = &Qh[((size_t)bh * S_ + q0 + wave * 16 + ln) * 64 + quad * 8];
  bf16x8 aq0 = ld_frag_u16(qp);
  bf16x8 aq1 = ld_frag_u16(qp + 32);

  float il4[4];
  #pragma unroll
  for (int rg = 0; rg < 4; ++rg){
    int row = q0 + wave * 16 + quad * 4 + rg;
    il4[rg] = 1.0f / lrow[bh * S_ + row];
  }
  f32x4 oacc[4];
  #pragma unroll
  for (int jd = 0; jd < 4; ++jd) oacc[jd] = (f32x4){0.f, 0.f, 0.f, 0.f};

  const u16* kp0 = &Kh[((size_t)bh * S_ + ln) * 64 + quad * 8];
  const u16* kp1 = kp0 + 16 * 64;
  const u16* kp2 = kp0 + 32 * 64;
  const u16* kp3 = kp0 + 48 * 64;
  // V^T fragment pointers, one per jd (rows jd*16+ln along d), bumped 64 cols/tile
  const u16* vp0 = &Vt[((size_t)bh * 64 + ln) * S_ + quad * 8];
  const u16* vp1 = vp0 + (size_t)16 * S_;
  const u16* vp2 = vp0 + (size_t)32 * S_;
  const u16* vp3 = vp0 + (size_t)48 * S_;
  const float* mp = &maskp[bsel * S_ + ln];
  float* ap = &attn[((size_t)bh * S_ + q0 + wave * 16 + quad * 4) * S_ + ln];
  u16* psw = &Ps[wave][(quad * 4) * 72 + ln];
  const u16* psr = &Ps[wave][ln * 72 + quad * 8];

  for (int n0 = 0; n0 < S_; n0 += 64){
    float mv0 = mp[ 0] * MASKC - SHIFT2;
    float mv1 = mp[16] * MASKC - SHIFT2;
    float mv2 = mp[32] * MASKC - SHIFT2;
    float mv3 = mp[48] * MASKC - SHIFT2;
    bf16x8 b00 = ld_frag_u16(kp0), b01 = ld_frag_u16(kp0 + 32);
    bf16x8 b10 = ld_frag_u16(kp1), b11 = ld_frag_u16(kp1 + 32);
    bf16x8 b20 = ld_frag_u16(kp2), b21 = ld_frag_u16(kp2 + 32);
    bf16x8 b30 = ld_frag_u16(kp3), b31 = ld_frag_u16(kp3 + 32);
    f32x4 a0 = {0.f,0.f,0.f,0.f}, a1 = a0, a2 = a0, a3 = a0;
    a0 = mma16(aq0, b00, a0); a0 = mma16(aq1, b01, a0);
    a1 = mma16(aq0, b10, a1); a1 = mma16(aq1, b11, a1);
    a2 = mma16(aq0, b20, a2); a2 = mma16(aq1, b21, a2);
    a3 = mma16(aq0, b30, a3); a3 = mma16(aq1, b31, a3);
    #pragma unroll
    for (int rg = 0; rg < 4; ++rg){
      float p0 = exp2f(a0[rg] * SCALE2 + mv0) * il4[rg];
      float p1 = exp2f(a1[rg] * SCALE2 + mv1) * il4[rg];
      float p2 = exp2f(a2[rg] * SCALE2 + mv2) * il4[rg];
      float p3 = exp2f(a3[rg] * SCALE2 + mv3) * il4[rg];
      float* arow = ap + (size_t)rg * S_ + n0;
      arow[ 0] = p0; arow[16] = p1; arow[32] = p2; arow[48] = p3;
      u16* pr = psw + rg * 72;
      pr[ 0] = f2b(p0); pr[16] = f2b(p1); pr[32] = f2b(p2); pr[48] = f2b(p3);
    }
    // Ps is per-wave: ds_write -> ds_read ordering via lgkmcnt, no barrier.
    #pragma unroll
    for (int kk = 0; kk < 2; ++kk){
      bf16x8 pa = ld_frag_u16(psr + kk * 32);
      bf16x8 v0 = ld_frag_u16(vp0 + n0 + kk * 32);
      bf16x8 v1 = ld_frag_u16(vp1 + n0 + kk * 32);
      bf16x8 v2 = ld_frag_u16(vp2 + n0 + kk * 32);
      bf16x8 v3 = ld_frag_u16(vp3 + n0 + kk * 32);
      oacc[0] = mma16(pa, v0, oacc[0]);
      oacc[1] = mma16(pa, v1, oacc[1]);
      oacc[2] = mma16(pa, v2, oacc[2]);
      oacc[3] = mma16(pa, v3, oacc[3]);
    }
    kp0 += 64 * 64; kp1 += 64 * 64; kp2 += 64 * 64; kp3 += 64 * 64;
    mp += 64;
  }
  const int b = bh >> 4, h = bh & 15;
  #pragma unroll
  for (int jd = 0; jd < 4; ++jd){
    #pragma unroll
    for (int rg = 0; rg < 4; ++rg){
      int row = q0 + wave * 16 + quad * 4 + rg;
      OH[((size_t)b * S_ + row) * D_ + h * 64 + jd * 16 + ln] = f2b(oacc[jd][rg]);
    }
  }
}

// ---------------------------------------------------------------------------
extern "C" void kernel_launch(void* const* d_in, const int* in_sizes, int n_in,
                              void* d_out, int out_size, void* d_ws, size_t ws_size,
                              hipStream_t stream)
{
  const float* q    = (const float*)d_in[0];
  const float* k    = (const float*)d_in[1];
  const float* v    = (const float*)d_in[2];
  const float* mask = (const float*)d_in[3];
  const float* wq   = (const float*)d_in[4];
  const float* bq   = (const float*)d_in[5];
  const float* wk   = (const float*)d_in[6];
  const float* bk   = (const float*)d_in[7];
  const float* wv   = (const float*)d_in[8];
  const float* bv   = (const float*)d_in[9];
  const float* wo   = (const float*)d_in[10];
  const float* bo   = (const float*)d_in[11];

  char* ws = (char*)d_ws;
  u16* wqT = (u16*)(ws + 0ull);          //  2 MB
  u16* wkT = (u16*)(ws + 2097152ull);
  u16* wvT = (u16*)(ws + 4194304ull);
  u16* woT = (u16*)(ws + 6291456ull);
  u16* qb  = (u16*)(ws + 8388608ull);    //  8 MB each
  u16* kb  = (u16*)(ws + 16777216ull);
  u16* vb  = (u16*)(ws + 25165824ull);   // reused as Vt after gemm_qkv
  u16* Qh  = (u16*)(ws + 33554432ull);
  u16* Kh  = (u16*)(ws + 41943040ull);
  u16* Vh  = (u16*)(ws + 50331648ull);
  u16* OH  = (u16*)(ws + 58720256ull);
  float* lrow = (float*)(ws + 67108864ull);
  u16* Vt  = vb;                          // vb is dead after gemm_qkv

  float* out  = (float*)d_out;
  float* attn = out + 4194304ull;  // [B,H,S,S] fp32

  prep<<<dim3(7168), 256, 0, stream>>>(q, k, v, qb, kb, vb,
                                       wq, wk, wv, wo, wqT, wkT, wvT, woT);
  gemm_qkv<<<dim3(32, 8, 3), 256, 0, stream>>>(qb, kb, vb, wqT, wkT, wvT,
                                               bq, bk, bv, Qh, Kh, Vh);
  vtrans<<<dim3(32, 32), 256, 0, stream>>>(Vh, Vt);
  attn_stats<<<dim3(32, 32), 256, 0, stream>>>(Qh, Kh, mask, lrow);
  attn_pv<<<dim3(32, 32), 256, 0, stream>>>(Qh, Kh, Vt, mask, lrow, attn, OH);
  gemm_o<<<dim3(32, 8), 256, 0, stream>>>(OH, woT, bo, out);
}

// Round 3
// 810.481 us; speedup vs baseline: 1.2216x; 1.2216x over previous
//
#include <hip/hip_runtime.h>

typedef unsigned short u16;
typedef unsigned int   u32;
typedef __bf16 bf16x8 __attribute__((ext_vector_type(8)));
typedef float  f32x4  __attribute__((ext_vector_type(4)));
typedef u16    u16x8  __attribute__((ext_vector_type(8)));

#define S_   2048
#define D_   1024
#define H_   16
#define M_   4096

// log2-domain softmax: p = exp2(s*SCALE2 + mask*MASKC - SHIFT2)
// fixed shift 8 replaces the row max (softmax shift-invariant; |s*0.125|<~12)
#define SCALE2 0.18033688011112042f
#define MASKC  (-1.4426950408889634e9f)
#define SHIFT2 11.541560327111707f

__device__ __forceinline__ u16 f2b(float f){
  union { float f; u32 i; } x; x.f = f;
  u32 u = x.i;
  u32 r = (u + 0x7fffu + ((u >> 16) & 1u)) >> 16;
  return (u16)r;
}
__device__ __forceinline__ void async16(u16* lds, const u16* g){
  __builtin_amdgcn_global_load_lds((const __attribute__((address_space(1))) void*)g,
                                   (__attribute__((address_space(3))) void*)lds, 16, 0, 0);
}
__device__ __forceinline__ f32x4 mma16(bf16x8 a, bf16x8 b, f32x4 c){
  return __builtin_amdgcn_mfma_f32_16x16x32_bf16(a, b, c, 0, 0, 0);
}
__device__ __forceinline__ bf16x8 ld_frag_u16(const u16* p){
  u16x8 v = *(const u16x8*)p;
  return __builtin_bit_cast(bf16x8, v);
}

// ---------------------------------------------------------------------------
// prep: fused  (a) q/k/v fp32->bf16 cvt   [blocks 0..6143]
//              (b) weight transpose+cvt   [blocks 6144..7167]
// ---------------------------------------------------------------------------
__global__ __launch_bounds__(256) void prep(
    const float* __restrict__ q, const float* __restrict__ k, const float* __restrict__ v,
    u16* __restrict__ qb, u16* __restrict__ kb, u16* __restrict__ vb,
    const float* __restrict__ w0, const float* __restrict__ w1,
    const float* __restrict__ w2, const float* __restrict__ w3,
    u16* __restrict__ t0, u16* __restrict__ t1,
    u16* __restrict__ t2, u16* __restrict__ t3)
{
  const int bid = blockIdx.x;
  if (bid < 6144){
    const int which = bid >> 11;
    const int bx = bid & 2047;
    const float* x = (which == 0) ? q : (which == 1) ? k : v;
    u16* y = (which == 0) ? qb : (which == 1) ? kb : vb;
    size_t i = (size_t)bx * 256 + threadIdx.x;
    const f32x4* p = (const f32x4*)(x + i * 8);
    f32x4 a = p[0], b = p[1];
    u16x8 o;
    o[0] = f2b(a[0]); o[1] = f2b(a[1]); o[2] = f2b(a[2]); o[3] = f2b(a[3]);
    o[4] = f2b(b[0]); o[5] = f2b(b[1]); o[6] = f2b(b[2]); o[7] = f2b(b[3]);
    *(u16x8*)(y + i * 8) = o;
  } else {
    const int b = bid - 6144;
    const int z = b >> 8, rem = b & 255, by = rem >> 4, bx = rem & 15;
    const float* W; u16* T;
    switch (z){
      case 0: W = w0; T = t0; break;
      case 1: W = w1; T = t1; break;
      case 2: W = w2; T = t2; break;
      default: W = w3; T = t3; break;
    }
    __shared__ u16 tile[64][65];
    const int t = threadIdx.x;
    const int r0 = by * 64, c0 = bx * 64;
    const int row = t >> 2, cg = t & 3;
    const float* src = W + (size_t)(r0 + row) * D_ + c0 + cg * 16;
    f32x4 a0 = *(const f32x4*)(src + 0);
    f32x4 a1 = *(const f32x4*)(src + 4);
    f32x4 a2 = *(const f32x4*)(src + 8);
    f32x4 a3 = *(const f32x4*)(src + 12);
    #pragma unroll
    for (int e = 0; e < 4; ++e){
      tile[row][cg*16 +      e] = f2b(a0[e]);
      tile[row][cg*16 +  4 + e] = f2b(a1[e]);
      tile[row][cg*16 +  8 + e] = f2b(a2[e]);
      tile[row][cg*16 + 12 + e] = f2b(a3[e]);
    }
    __syncthreads();
    u16* dst = T + (size_t)(c0 + row) * D_ + r0 + cg * 16;
    u16x8 oa, ob;
    #pragma unroll
    for (int e = 0; e < 8; ++e){ oa[e] = tile[cg*16 + e][row]; ob[e] = tile[cg*16 + 8 + e][row]; }
    *(u16x8*)dst = oa;
    *(u16x8*)(dst + 8) = ob;
  }
}

// ---------------------------------------------------------------------------
// gemm_qkv: fused Q/K/V projections. Epilogue round-trips the 128x128 C tile
// through LDS (reusing As/Bs space) for 16B-coalesced stores; z==2 writes the
// tile TRANSPOSED, producing Vt [bh,64,S] directly (kills the 4KB-stride
// 2B scatter the old mode-2 epilogue had).
// ---------------------------------------------------------------------------
__global__ __launch_bounds__(256) void gemm_qkv(
    const u16* __restrict__ qb, const u16* __restrict__ kb, const u16* __restrict__ vb,
    const u16* __restrict__ wqT, const u16* __restrict__ wkT, const u16* __restrict__ wvT,
    const float* __restrict__ bq, const float* __restrict__ bk, const float* __restrict__ bv,
    u16* __restrict__ Qh, u16* __restrict__ Kh, u16* __restrict__ Vt)
{
  __shared__ __attribute__((aligned(16))) u16 smem[128 * 132]; // As|Bs, then Ct[128][132]
  u16* As = smem;
  u16* Bs = smem + 128 * 64;
  const u16 *A, *Bt; const float* bias; u16* Cb;
  switch (blockIdx.z){
    case 0: A = qb; Bt = wqT; bias = bq; Cb = Qh; break;
    case 1: A = kb; Bt = wkT; bias = bk; Cb = Kh; break;
    default: A = vb; Bt = wvT; bias = bv; Cb = Vt; break;
  }
  const bool vtr = (blockIdx.z == 2);
  const int tid = threadIdx.x;
  const int wave = tid >> 6, lane = tid & 63, ln = lane & 15, quad = lane >> 4;
  const int wm = wave >> 1, wn = wave & 1;
  const int m0 = blockIdx.x * 128, n0 = blockIdx.y * 128;

  f32x4 acc[4][4];
  #pragma unroll
  for (int i = 0; i < 4; ++i)
    #pragma unroll
    for (int j = 0; j < 4; ++j) acc[i][j] = (f32x4){0.f, 0.f, 0.f, 0.f};

  for (int kt = 0; kt < D_; kt += 64){
    #pragma unroll
    for (int it = 0; it < 4; ++it){
      int i = it * 256 + tid;
      int r = i >> 3, c = i & 7, cs = c ^ (r & 7);
      async16(&As[i * 8], &A [(size_t)(m0 + r) * D_ + kt + cs * 8]);
      async16(&Bs[i * 8], &Bt[(size_t)(n0 + r) * D_ + kt + cs * 8]);
    }
    __syncthreads();
    #pragma unroll
    for (int kk = 0; kk < 2; ++kk){
      bf16x8 af[4], bfr[4];
      #pragma unroll
      for (int i4 = 0; i4 < 4; ++i4){
        int row = wm * 64 + i4 * 16 + ln;
        af[i4] = ld_frag_u16(&As[row * 64 + ((kk * 4 + quad) ^ (row & 7)) * 8]);
      }
      #pragma unroll
      for (int j4 = 0; j4 < 4; ++j4){
        int row = wn * 64 + j4 * 16 + ln;
        bfr[j4] = ld_frag_u16(&Bs[row * 64 + ((kk * 4 + quad) ^ (row & 7)) * 8]);
      }
      #pragma unroll
      for (int i4 = 0; i4 < 4; ++i4)
        #pragma unroll
        for (int j4 = 0; j4 < 4; ++j4)
          acc[i4][j4] = mma16(af[i4], bfr[j4], acc[i4][j4]);
    }
    __syncthreads();
  }

  // ---- epilogue: bias add -> bf16 -> LDS tile -> coalesced 16B stores ----
  #pragma unroll
  for (int j4 = 0; j4 < 4; ++j4){
    int nl = wn * 64 + j4 * 16 + ln;
    float biasv = bias[n0 + nl];
    #pragma unroll
    for (int i4 = 0; i4 < 4; ++i4){
      #pragma unroll
      for (int rg = 0; rg < 4; ++rg){
        int ml = wm * 64 + i4 * 16 + quad * 4 + rg;
        u16 hv = f2b(acc[i4][j4][rg] + biasv);
        smem[vtr ? (nl * 132 + ml) : (ml * 132 + nl)] = hv;
      }
    }
  }
  __syncthreads();
  const int bb = m0 >> 11, sbase = m0 & 2047;
  #pragma unroll
  for (int c = 0; c < 8; ++c){
    int task = c * 256 + tid;         // 0..2047: 128 rows x 16 chunks of 8 u16
    int rr = task >> 4, ch = task & 15;
    u16x8 val = *(const u16x8*)&smem[rr * 132 + ch * 8];
    if (vtr){
      int hh = (n0 + rr) >> 6, dc = (n0 + rr) & 63;
      *(u16x8*)&Cb[((size_t)(bb * H_ + hh) * 64 + dc) * S_ + sbase + ch * 8] = val;
    } else {
      int s = sbase + rr;
      int nn = n0 + ch * 8, hh = nn >> 6, dc = nn & 63;
      *(u16x8*)&Cb[((size_t)(bb * H_ + hh) * S_ + s) * 64 + dc] = val;
    }
  }
}

// ---------------------------------------------------------------------------
// gemm_o: output projection, fp32 C. Double-buffered LDS prefetch.
// ---------------------------------------------------------------------------
__global__ __launch_bounds__(256) void gemm_o(
    const u16* __restrict__ A, const u16* __restrict__ Bt,
    const float* __restrict__ bias, float* __restrict__ Cf)
{
  __shared__ __attribute__((aligned(16))) u16 As[2][128 * 64];
  __shared__ __attribute__((aligned(16))) u16 Bs[2][128 * 64];
  const int tid = threadIdx.x;
  const int wave = tid >> 6, lane = tid & 63, ln = lane & 15, quad = lane >> 4;
  const int wm = wave >> 1, wn = wave & 1;
  const int m0 = blockIdx.x * 128, n0 = blockIdx.y * 128;

  f32x4 acc[4][4];
  #pragma unroll
  for (int i = 0; i < 4; ++i)
    #pragma unroll
    for (int j = 0; j < 4; ++j) acc[i][j] = (f32x4){0.f, 0.f, 0.f, 0.f};

  #pragma unroll
  for (int it = 0; it < 4; ++it){
    int i = it * 256 + tid;
    int r = i >> 3, c = i & 7, cs = c ^ (r & 7);
    async16(&As[0][i * 8], &A [(size_t)(m0 + r) * D_ + cs * 8]);
    async16(&Bs[0][i * 8], &Bt[(size_t)(n0 + r) * D_ + cs * 8]);
  }
  __syncthreads();

  int cur = 0;
  for (int kt = 0; kt < D_; kt += 64){
    if (kt + 64 < D_){
      int nb = cur ^ 1;
      #pragma unroll
      for (int it = 0; it < 4; ++it){
        int i = it * 256 + tid;
        int r = i >> 3, c = i & 7, cs = c ^ (r & 7);
        async16(&As[nb][i * 8], &A [(size_t)(m0 + r) * D_ + kt + 64 + cs * 8]);
        async16(&Bs[nb][i * 8], &Bt[(size_t)(n0 + r) * D_ + kt + 64 + cs * 8]);
      }
    }
    #pragma unroll
    for (int kk = 0; kk < 2; ++kk){
      bf16x8 af[4], bfr[4];
      #pragma unroll
      for (int i4 = 0; i4 < 4; ++i4){
        int row = wm * 64 + i4 * 16 + ln;
        af[i4] = ld_frag_u16(&As[cur][row * 64 + ((kk * 4 + quad) ^ (row & 7)) * 8]);
      }
      #pragma unroll
      for (int j4 = 0; j4 < 4; ++j4){
        int row = wn * 64 + j4 * 16 + ln;
        bfr[j4] = ld_frag_u16(&Bs[cur][row * 64 + ((kk * 4 + quad) ^ (row & 7)) * 8]);
      }
      #pragma unroll
      for (int i4 = 0; i4 < 4; ++i4)
        #pragma unroll
        for (int j4 = 0; j4 < 4; ++j4)
          acc[i4][j4] = mma16(af[i4], bfr[j4], acc[i4][j4]);
    }
    __syncthreads();
    cur ^= 1;
  }

  #pragma unroll
  for (int j4 = 0; j4 < 4; ++j4){
    int nidx = n0 + wn * 64 + j4 * 16 + ln;
    float biasv = bias[nidx];
    #pragma unroll
    for (int i4 = 0; i4 < 4; ++i4){
      #pragma unroll
      for (int rg = 0; rg < 4; ++rg){
        int r = m0 + wm * 64 + i4 * 16 + quad * 4 + rg;
        Cf[(size_t)r * D_ + nidx] = acc[i4][j4][rg] + biasv;
      }
    }
  }
}

// ---------------------------------------------------------------------------
// Pass 1: softmax denominator, fixed shift. QBLK=128 (2 Q row-groups/wave),
// double-buffered K staging, XCD-pinned bh (all q-blocks of a bh on one XCD
// -> K stays in that XCD's L2). Grid: 512 blocks flattened.
// ---------------------------------------------------------------------------
__global__ __launch_bounds__(256) void attn_stats(
    const u16* __restrict__ Qh, const u16* __restrict__ Kh,
    const float* __restrict__ maskp, float* __restrict__ lrow)
{
  __shared__ __attribute__((aligned(16))) u16 Qs[128 * 64];
  __shared__ __attribute__((aligned(16))) u16 Ks[2][64 * 64];
  const int tid = threadIdx.x;
  const int wave = tid >> 6, lane = tid & 63, ln = lane & 15, quad = lane >> 4;
  const int orig = blockIdx.x;          // 512
  const int xcd = orig & 7, slot = orig >> 3;
  const int bh = xcd * 4 + (slot >> 4); // 4 bh per XCD
  const int q0 = (slot & 15) * 128;
  const int bsel = bh >> 4;

  #pragma unroll
  for (int it = 0; it < 4; ++it){
    int i = it * 256 + tid;
    int r = i >> 3, c = i & 7, cs = c ^ (r & 7);
    async16(&Qs[i * 8], &Qh[((size_t)bh * S_ + q0 + r) * 64 + cs * 8]);
  }
  #pragma unroll
  for (int it = 0; it < 2; ++it){
    int i = it * 256 + tid;
    int r = i >> 3, c = i & 7, cs = c ^ (r & 7);
    async16(&Ks[0][i * 8], &Kh[((size_t)bh * S_ + r) * 64 + cs * 8]);
  }
  __syncthreads();
  bf16x8 aq[2][2];
  #pragma unroll
  for (int f = 0; f < 2; ++f){
    int row = wave * 32 + f * 16 + ln;
    aq[f][0] = ld_frag_u16(&Qs[row * 64 + ((0 + quad) ^ (row & 7)) * 8]);
    aq[f][1] = ld_frag_u16(&Qs[row * 64 + ((4 + quad) ^ (row & 7)) * 8]);
  }

  float lsum[2][4] = {{0.f,0.f,0.f,0.f},{0.f,0.f,0.f,0.f}};
  int cur = 0;
  for (int n0 = 0; n0 < S_; n0 += 64){
    if (n0 + 64 < S_){
      int nb = cur ^ 1;
      #pragma unroll
      for (int it = 0; it < 2; ++it){
        int i = it * 256 + tid;
        int r = i >> 3, c = i & 7, cs = c ^ (r & 7);
        async16(&Ks[nb][i * 8], &Kh[((size_t)bh * S_ + n0 + 64 + r) * 64 + cs * 8]);
      }
    }
    float mv[4];
    #pragma unroll
    for (int j = 0; j < 4; ++j)
      mv[j] = maskp[bsel * S_ + n0 + j * 16 + ln] * MASKC - SHIFT2;
    #pragma unroll
    for (int j = 0; j < 4; ++j){
      int row = j * 16 + ln;
      bf16x8 b0 = ld_frag_u16(&Ks[cur][row * 64 + ((0 + quad) ^ (row & 7)) * 8]);
      bf16x8 b1 = ld_frag_u16(&Ks[cur][row * 64 + ((4 + quad) ^ (row & 7)) * 8]);
      #pragma unroll
      for (int f = 0; f < 2; ++f){
        f32x4 a = {0.f, 0.f, 0.f, 0.f};
        a = mma16(aq[f][0], b0, a);
        a = mma16(aq[f][1], b1, a);
        #pragma unroll
        for (int rg = 0; rg < 4; ++rg)
          lsum[f][rg] += exp2f(a[rg] * SCALE2 + mv[j]);
      }
    }
    __syncthreads();
    cur ^= 1;
  }
  #pragma unroll
  for (int f = 0; f < 2; ++f)
    #pragma unroll
    for (int rg = 0; rg < 4; ++rg){
      float s = lsum[f][rg];
      s += __shfl_xor(s, 1);
      s += __shfl_xor(s, 2);
      s += __shfl_xor(s, 4);
      s += __shfl_xor(s, 8);
      if (ln == 0)
        lrow[bh * S_ + q0 + wave * 32 + f * 16 + quad * 4 + rg] = s;
    }
}

// ---------------------------------------------------------------------------
// Pass 2: QBLK=128, Q frags in registers, K/V double-buffered in LDS,
// per-wave Ps round-trip (lgkmcnt-ordered), PV accumulate. XCD-pinned bh.
// ---------------------------------------------------------------------------
__global__ __launch_bounds__(256) void attn_pv(
    const u16* __restrict__ Qh, const u16* __restrict__ Kh, const u16* __restrict__ Vt,
    const float* __restrict__ maskp, const float* __restrict__ lrow,
    float* __restrict__ attn, u16* __restrict__ OH)
{
  __shared__ __attribute__((aligned(16))) u16 Ks[2][64 * 64];
  __shared__ __attribute__((aligned(16))) u16 Vs[2][64 * 64];
  __shared__ __attribute__((aligned(16))) u16 Ps[4][32 * 72];
  const int tid = threadIdx.x;
  const int wave = tid >> 6, lane = tid & 63, ln = lane & 15, quad = lane >> 4;
  const int orig = blockIdx.x;          // 512
  const int xcd = orig & 7, slot = orig >> 3;
  const int bh = xcd * 4 + (slot >> 4);
  const int q0 = (slot & 15) * 128;
  const int bsel = bh >> 4;

  // Q fragments straight from global (one-time, 16B/lane)
  bf16x8 aq[2][2];
  #pragma unroll
  for (int f = 0; f < 2; ++f){
    const u16* qp = &Qh[((size_t)bh * S_ + q0 + wave * 32 + f * 16 + ln) * 64 + quad * 8];
    aq[f][0] = ld_frag_u16(qp);
    aq[f][1] = ld_frag_u16(qp + 32);
  }
  float il[2][4];
  #pragma unroll
  for (int f = 0; f < 2; ++f)
    #pragma unroll
    for (int rg = 0; rg < 4; ++rg){
      int row = q0 + wave * 32 + f * 16 + quad * 4 + rg;
      il[f][rg] = 1.0f / lrow[bh * S_ + row];
    }
  f32x4 oacc[2][4];
  #pragma unroll
  for (int f = 0; f < 2; ++f)
    #pragma unroll
    for (int jd = 0; jd < 4; ++jd) oacc[f][jd] = (f32x4){0.f, 0.f, 0.f, 0.f};

  #pragma unroll
  for (int it = 0; it < 2; ++it){
    int i = it * 256 + tid;
    int r = i >> 3, c = i & 7, cs = c ^ (r & 7);
    async16(&Ks[0][i * 8], &Kh[((size_t)bh * S_ + r) * 64 + cs * 8]);
    async16(&Vs[0][i * 8], &Vt[((size_t)bh * 64 + r) * S_ + cs * 8]);
  }
  __syncthreads();

  int cur = 0;
  for (int n0 = 0; n0 < S_; n0 += 64){
    if (n0 + 64 < S_){
      int nb = cur ^ 1;
      #pragma unroll
      for (int it = 0; it < 2; ++it){
        int i = it * 256 + tid;
        int r = i >> 3, c = i & 7, cs = c ^ (r & 7);
        async16(&Ks[nb][i * 8], &Kh[((size_t)bh * S_ + n0 + 64 + r) * 64 + cs * 8]);
        async16(&Vs[nb][i * 8], &Vt[((size_t)bh * 64 + r) * S_ + n0 + 64 + cs * 8]);
      }
    }
    float mv[4];
    #pragma unroll
    for (int j = 0; j < 4; ++j)
      mv[j] = maskp[bsel * S_ + n0 + j * 16 + ln] * MASKC - SHIFT2;
    #pragma unroll
    for (int j = 0; j < 4; ++j){
      int row = j * 16 + ln;
      bf16x8 b0 = ld_frag_u16(&Ks[cur][row * 64 + ((0 + quad) ^ (row & 7)) * 8]);
      bf16x8 b1 = ld_frag_u16(&Ks[cur][row * 64 + ((4 + quad) ^ (row & 7)) * 8]);
      #pragma unroll
      for (int f = 0; f < 2; ++f){
        f32x4 a = {0.f, 0.f, 0.f, 0.f};
        a = mma16(aq[f][0], b0, a);
        a = mma16(aq[f][1], b1, a);
        #pragma unroll
        for (int rg = 0; rg < 4; ++rg){
          float p = exp2f(a[rg] * SCALE2 + mv[j]) * il[f][rg];
          attn[((size_t)bh * S_ + q0 + wave * 32 + f * 16 + quad * 4 + rg) * S_ + n0 + j * 16 + ln] = p;
          Ps[wave][(f * 16 + quad * 4 + rg) * 72 + j * 16 + ln] = f2b(p);
        }
      }
    }
    // Ps is per-wave: ds_write -> ds_read ordering via lgkmcnt, no barrier.
    #pragma unroll
    for (int f = 0; f < 2; ++f){
      #pragma unroll
      for (int kk = 0; kk < 2; ++kk){
        bf16x8 pa = ld_frag_u16(&Ps[wave][(f * 16 + ln) * 72 + kk * 32 + quad * 8]);
        #pragma unroll
        for (int jd = 0; jd < 4; ++jd){
          int row = jd * 16 + ln;
          bf16x8 vb = ld_frag_u16(&Vs[cur][row * 64 + ((kk * 4 + quad) ^ (row & 7)) * 8]);
          oacc[f][jd] = mma16(pa, vb, oacc[f][jd]);
        }
      }
    }
    __syncthreads();
    cur ^= 1;
  }
  const int b = bh >> 4, h = bh & 15;
  #pragma unroll
  for (int f = 0; f < 2; ++f)
    #pragma unroll
    for (int jd = 0; jd < 4; ++jd)
      #pragma unroll
      for (int rg = 0; rg < 4; ++rg){
        int row = q0 + wave * 32 + f * 16 + quad * 4 + rg;
        OH[((size_t)b * S_ + row) * D_ + h * 64 + jd * 16 + ln] = f2b(oacc[f][jd][rg]);
      }
}

// ---------------------------------------------------------------------------
extern "C" void kernel_launch(void* const* d_in, const int* in_sizes, int n_in,
                              void* d_out, int out_size, void* d_ws, size_t ws_size,
                              hipStream_t stream)
{
  const float* q    = (const float*)d_in[0];
  const float* k    = (const float*)d_in[1];
  const float* v    = (const float*)d_in[2];
  const float* mask = (const float*)d_in[3];
  const float* wq   = (const float*)d_in[4];
  const float* bq   = (const float*)d_in[5];
  const float* wk   = (const float*)d_in[6];
  const float* bk   = (const float*)d_in[7];
  const float* wv   = (const float*)d_in[8];
  const float* bv   = (const float*)d_in[9];
  const float* wo   = (const float*)d_in[10];
  const float* bo   = (const float*)d_in[11];

  char* ws = (char*)d_ws;
  u16* wqT = (u16*)(ws + 0ull);
  u16* wkT = (u16*)(ws + 2097152ull);
  u16* wvT = (u16*)(ws + 4194304ull);
  u16* woT = (u16*)(ws + 6291456ull);
  u16* qb  = (u16*)(ws + 8388608ull);
  u16* kb  = (u16*)(ws + 16777216ull);
  u16* vb  = (u16*)(ws + 25165824ull);
  u16* Qh  = (u16*)(ws + 33554432ull);
  u16* Kh  = (u16*)(ws + 41943040ull);
  u16* Vt  = (u16*)(ws + 50331648ull);
  u16* OH  = (u16*)(ws + 58720256ull);
  float* lrow = (float*)(ws + 67108864ull);

  float* out  = (float*)d_out;
  float* attn = out + 4194304ull;  // [B,H,S,S] fp32

  prep<<<dim3(7168), 256, 0, stream>>>(q, k, v, qb, kb, vb,
                                       wq, wk, wv, wo, wqT, wkT, wvT, woT);
  gemm_qkv<<<dim3(32, 8, 3), 256, 0, stream>>>(qb, kb, vb, wqT, wkT, wvT,
                                               bq, bk, bv, Qh, Kh, Vt);
  attn_stats<<<dim3(512), 256, 0, stream>>>(Qh, Kh, mask, lrow);
  attn_pv<<<dim3(512), 256, 0, stream>>>(Qh, Kh, Vt, mask, lrow, attn, OH);
  gemm_o<<<dim3(32, 8), 256, 0, stream>>>(OH, woT, bo, out);
}